// Round 1
// baseline (227.713 us; speedup 1.0000x reference)
//
#include <hip/hip_runtime.h>

// FWHT over last dim (n = 4096), normalized by 1/sqrt(4096) = 1/64.
// One block (256 threads) per row. Row staged in 16 KiB LDS.
// 12 butterfly bits split into 3 register phases of 4 bits each:
//   P1: bits {0,1,10,11}  (float4 components e=bits0..1, reg j=bits10..11)
//   P2: bits {2..5}       (via LDS exchange)
//   P3: bits {6..9}       (via LDS exchange)
// All LDS addresses pass through the same XOR swizzle S(A)=A^(((A>>6)&7)<<2)
// (a fixed bijection -> correctness-neutral) to kill transpose bank conflicts.

__device__ __forceinline__ float4 f4add(float4 a, float4 b) {
    return make_float4(a.x + b.x, a.y + b.y, a.z + b.z, a.w + b.w);
}
__device__ __forceinline__ float4 f4sub(float4 a, float4 b) {
    return make_float4(a.x - b.x, a.y - b.y, a.z - b.z, a.w - b.w);
}

__global__ void __launch_bounds__(256) fwht4096_kernel(const float* __restrict__ in,
                                                       float* __restrict__ out) {
    __shared__ float lds[4096];
    const int t = threadIdx.x;
    const size_t base = (size_t)blockIdx.x * 4096;

    // ---------------- P1: bits {0,1,10,11} ----------------
    // element index i = e + 4*t + 1024*j   (e=0..3 in float4, j=0..3 regs)
    const float4* rin4 = reinterpret_cast<const float4*>(in + base);
    float4 v[4];
#pragma unroll
    for (int j = 0; j < 4; ++j) v[j] = rin4[t + 256 * j];

    // Hadamard over e (bits 0,1): pairs (x,y),(z,w) then (x,z),(y,w)
#pragma unroll
    for (int j = 0; j < 4; ++j) {
        float ab  = v[j].x + v[j].y, amb = v[j].x - v[j].y;
        float cd  = v[j].z + v[j].w, cmd = v[j].z - v[j].w;
        v[j] = make_float4(ab + cd, amb + cmd, ab - cd, amb - cmd);
    }
    // Hadamard over j (bits 10,11)
    {
        float4 s0 = f4add(v[0], v[1]), d0 = f4sub(v[0], v[1]);
        float4 s1 = f4add(v[2], v[3]), d1 = f4sub(v[2], v[3]);
        v[0] = f4add(s0, s1); v[2] = f4sub(s0, s1);
        v[1] = f4add(d0, d1); v[3] = f4sub(d0, d1);
    }

    // Write to LDS as float4. Logical dword addr A = 4t + 1024j.
    // S(A) = (4t ^ (((t>>4)&7)<<2)) + 1024j  ->  float4 index (t ^ ((t>>4)&7)) + 256j.
    {
        float4* l4 = reinterpret_cast<float4*>(lds);
        const int wb = t ^ ((t >> 4) & 7);
#pragma unroll
        for (int j = 0; j < 4; ++j) l4[wb + 256 * j] = v[j];
    }
    __syncthreads();

    // ---------------- P2: bits {2..5} ----------------
    // element index i = (t&3) + 4*r + 64*(t>>2), r = 0..15
    // S maps 4*r -> 4*(r ^ s2) with s2 = (t>>2)&7 (bits 6..8 of A).
    float x[16];
    {
        const int b2 = (t & 3) + 64 * (t >> 2);
        const int s2 = (t >> 2) & 7;
#pragma unroll
        for (int r = 0; r < 16; ++r) x[r] = lds[b2 + 4 * (r ^ s2)];

#pragma unroll
        for (int h = 1; h < 16; h <<= 1) {
#pragma unroll
            for (int i = 0; i < 16; ++i) {
                if (!(i & h)) {
                    float a = x[i], b = x[i ^ h];
                    x[i] = a + b; x[i ^ h] = a - b;
                }
            }
        }
#pragma unroll
        for (int r = 0; r < 16; ++r) lds[b2 + 4 * (r ^ s2)] = x[r];
    }
    __syncthreads();

    // ---------------- P3: bits {6..9} ----------------
    // element index i = l + 64*r + 1024*w, l = t&63, w = t>>6
    // S xors (r&7)<<2 into the low-6 (lane) part.
    {
        const int l = t & 63, w = t >> 6;
        const int b3 = 1024 * w;
#pragma unroll
        for (int r = 0; r < 16; ++r)
            x[r] = lds[(l ^ ((r & 7) << 2)) + 64 * r + b3];

#pragma unroll
        for (int h = 1; h < 16; h <<= 1) {
#pragma unroll
            for (int i = 0; i < 16; ++i) {
                if (!(i & h)) {
                    float a = x[i], b = x[i ^ h];
                    x[i] = a + b; x[i ^ h] = a - b;
                }
            }
        }

        const float scale = 0.015625f;  // 1/64 = 1/sqrt(4096), exact
#pragma unroll
        for (int r = 0; r < 16; ++r)
            out[base + l + 64 * r + b3] = x[r] * scale;
    }
}

extern "C" void kernel_launch(void* const* d_in, const int* in_sizes, int n_in,
                              void* d_out, int out_size, void* d_ws, size_t ws_size,
                              hipStream_t stream) {
    const float* x = (const float*)d_in[0];
    float* out = (float*)d_out;
    const int rows = in_sizes[0] >> 12;  // / 4096
    fwht4096_kernel<<<dim3(rows), dim3(256), 0, stream>>>(x, out);
}

// Round 2
// 217.348 us; speedup vs baseline: 1.0477x; 1.0477x over previous
//
#include <hip/hip_runtime.h>

// FWHT over last dim (n = 4096), normalized by 1/64. One block (256 thr) per row.
// 12 butterfly bits in 3 register phases (butterflies commute, any order works):
//   P1: bits {0,1,10,11}  (from float4 global load: e=bits0..1, reg j=bits10..11)
//   P2: bits {2..5}       (LDS exchange, scalar b32, 2-way banks max = free)
//   P3: bits {6..9}       (LDS exchange)
// Final gather pass: P3 writes back to LDS, then conflict-free ds_read_b128 +
// nontemporal global_store_dwordx4 (was 16 scalar dword stores/thread).
// All LDS addresses use the involutive XOR swizzle S(A) = A ^ (((A>>6)&7)<<2)
// (fixed bijection on dword addrs -> correctness-neutral). Verified bank math:
//   P1 write / gather read: b128 at float4 idx (t ^ ((t>>4)&7)) + 256j -> per-16-lane
//     permutation of canonical pattern -> conflict-free.
//   P2 r/w: bank = (t&3) + 4*((r&7)^((t>>2)&7)) -> 32 distinct banks per half-wave,
//     2-way across halves -> free (m136).
//   P3 r/w: physical bank = l&31 -> 2-way -> free.

using v4 = __attribute__((ext_vector_type(4))) float;

__device__ __forceinline__ void had16(float x[16]) {
#pragma unroll
    for (int h = 1; h < 16; h <<= 1) {
#pragma unroll
        for (int i = 0; i < 16; ++i) {
            if (!(i & h)) {
                float a = x[i], b = x[i ^ h];
                x[i] = a + b; x[i ^ h] = a - b;
            }
        }
    }
}

__global__ void __launch_bounds__(256) fwht4096_kernel(const float* __restrict__ in,
                                                       float* __restrict__ out) {
    __shared__ float lds[4096];
    const int t = threadIdx.x;
    const size_t base = (size_t)blockIdx.x * 4096;
    const v4* in4 = reinterpret_cast<const v4*>(in + base);
    v4* out4 = reinterpret_cast<v4*>(out + base);

    // ---------------- P1: bits {0,1,10,11} ----------------
    v4 v[4];
#pragma unroll
    for (int j = 0; j < 4; ++j) v[j] = __builtin_nontemporal_load(&in4[t + 256 * j]);

#pragma unroll
    for (int j = 0; j < 4; ++j) {  // bits 0,1 (within float4)
        float a = v[j][0], b = v[j][1], c = v[j][2], d = v[j][3];
        float ab = a + b, amb = a - b, cd = c + d, cmd = c - d;
        v[j][0] = ab + cd; v[j][1] = amb + cmd; v[j][2] = ab - cd; v[j][3] = amb - cmd;
    }
    {  // bits 10,11 (across j)
        v4 s0 = v[0] + v[1], d0 = v[0] - v[1];
        v4 s1 = v[2] + v[3], d1 = v[2] - v[3];
        v[0] = s0 + s1; v[2] = s0 - s1;
        v[1] = d0 + d1; v[3] = d0 - d1;
    }
    {  // LDS write at S(4t + 1024j): float4 idx (t ^ ((t>>4)&7)) + 256j
        v4* l4 = reinterpret_cast<v4*>(lds);
        const int wb = t ^ ((t >> 4) & 7);
#pragma unroll
        for (int j = 0; j < 4; ++j) l4[wb + 256 * j] = v[j];
    }
    __syncthreads();

    float x[16];

    // ---------------- P2: bits {2..5} ----------------
    // logical elem = (t&3) + 4r + 64*(t>>2); physical = logical with r ^= s2
    {
        const int b2 = (t & 3) + 64 * (t >> 2);
        const int s2 = (t >> 2) & 7;
#pragma unroll
        for (int r = 0; r < 16; ++r) x[r] = lds[b2 + 4 * (r ^ s2)];
        had16(x);
#pragma unroll
        for (int r = 0; r < 16; ++r) lds[b2 + 4 * (r ^ s2)] = x[r];
    }
    __syncthreads();

    // ---------------- P3: bits {6..9} ----------------
    // logical elem = l + 64r + 1024w; physical low-6 = l ^ ((r&7)<<2)
    {
        const int l = t & 63, w = t >> 6;
        const int b3 = 1024 * w;
#pragma unroll
        for (int r = 0; r < 16; ++r) x[r] = lds[(l ^ ((r & 7) << 2)) + 64 * r + b3];
        had16(x);
        const float scale = 0.015625f;  // 1/64 = 1/sqrt(4096), exact
#pragma unroll
        for (int r = 0; r < 16; ++r) lds[(l ^ ((r & 7) << 2)) + 64 * r + b3] = x[r] * scale;
    }
    __syncthreads();

    // ---------------- Gather + vectorized nontemporal store ----------------
    {
        const v4* l4 = reinterpret_cast<const v4*>(lds);
        const int wb = t ^ ((t >> 4) & 7);
#pragma unroll
        for (int j = 0; j < 4; ++j) {
            v4 o = l4[wb + 256 * j];
            __builtin_nontemporal_store(o, &out4[t + 256 * j]);
        }
    }
}

extern "C" void kernel_launch(void* const* d_in, const int* in_sizes, int n_in,
                              void* d_out, int out_size, void* d_ws, size_t ws_size,
                              hipStream_t stream) {
    const float* x = (const float*)d_in[0];
    float* out = (float*)d_out;
    const int rows = in_sizes[0] >> 12;  // / 4096
    fwht4096_kernel<<<dim3(rows), dim3(256), 0, stream>>>(x, out);
}